// Round 14
// baseline (99.509 us; speedup 1.0000x reference)
//
#include <hip/hip_runtime.h>
#include <hip/hip_bf16.h>

typedef __bf16 bf16_8 __attribute__((ext_vector_type(8)));
typedef _Float16 f16x8 __attribute__((ext_vector_type(8)));
typedef float f32x4 __attribute__((ext_vector_type(4)));
typedef float f32x16 __attribute__((ext_vector_type(16)));

#define MFMA_BF(A, B, C)    __builtin_amdgcn_mfma_f32_16x16x32_bf16(A, B, C, 0, 0, 0)
#define MFMA_F16(A, B, C)   __builtin_amdgcn_mfma_f32_16x16x32_f16(A, B, C, 0, 0, 0)
#define MFMA32_F16(A, B, C) __builtin_amdgcn_mfma_f32_32x32x16_f16(A, B, C, 0, 0, 0)
#define MFMA32_BF(A, B, C)  __builtin_amdgcn_mfma_f32_32x32x16_bf16(A, B, C, 0, 0, 0)

#define BATCH 8
#define NPOS 4096            // 64*64 spatial
#define CIN 256
#define CMID 64
#define OC 256
#define NROWS (BATCH * NPOS) // 32768
#define NSPLIT 4             // j-split (nsplit=8 regressed: reg cap is 16 waves/CU)
#define LOG2E 1.44269504088896f

// lane i <-> lane i+32 register swap (hi half of a <-> lo half of b)
__device__ inline void swaplane32(unsigned& a, unsigned& b) {
    asm volatile("v_permlane32_swap_b32 %0, %1" : "+v"(a), "+v"(b));
}

// single-instruction 2^x. R11 LESSON: bare inline-asm v_exp_f32 is WRONG —
// trans-op forwarding hazard invisible to the compiler. Builtin is safe.
#if __has_builtin(__builtin_amdgcn_exp2f)
__device__ inline float fexp2(float x) { return __builtin_amdgcn_exp2f(x); }
#else
__device__ inline float fexp2(float x) {
    float r;
    asm("v_exp_f32 %0, %1\n\ts_nop 1" : "=v"(r) : "v"(x));  // nop INSIDE blob
    return r;
}
#endif

// ---------------------------------------------------------------------------
// wprep_kernel: WT[m][col][k] = W_m[k][col] * (m==0 ? log2e : 1), fp16.
// 3*64*256 = 49152 elements; grid 48 x 256, 4 elements (one uint2) each.
// ---------------------------------------------------------------------------
__global__ __launch_bounds__(256) void wprep_kernel(
    const float* __restrict__ Wk, const float* __restrict__ Wq,
    const float* __restrict__ Wv, _Float16* __restrict__ WT)
{
    int idx = (blockIdx.x * 256 + threadIdx.x) * 4;
    int m = idx >> 14;
    int rem = idx & 16383;
    int col = rem >> 8;
    int k0 = rem & 255;
    const float* W = (m == 0) ? Wk : (m == 1) ? Wq : Wv;
    float sc = (m == 0) ? LOG2E : 1.0f;
    union { _Float16 h[4]; uint2 u; } o;
    #pragma unroll
    for (int r = 0; r < 4; ++r)
        o.h[r] = (_Float16)(W[(k0 + r) * CMID + col] * sc);
    *(uint2*)(WT + idx) = o.u;
}

// ---------------------------------------------------------------------------
// proj_kernel v2: k,q,v = x @ {Wk,Wq,Wv}. x read ONCE into registers, m-loop
// in-block; W B-fragments loaded as contiguous f16x8 from global WT (96 KB,
// L2-hot, shared by all 512 blocks) — no W staging, ONE barrier total.
// LDS: only the 2-buffer output repack (18.4 KB). grid 512, block 256.
// ---------------------------------------------------------------------------
__global__ __launch_bounds__(256) void proj_kernel(
    const float* __restrict__ x,
    const _Float16* __restrict__ WT,    // [3][64][256]
    _Float16* __restrict__ k_ws, _Float16* __restrict__ q_ws,
    __bf16* __restrict__ vT_ws)
{
    const int r0 = blockIdx.x * 64;

    __shared__ _Float16 rp[2][64][72];  // k,q repack buffers

    const int lane = threadIdx.x & 63;
    const int wv = threadIdx.x >> 6;
    const int kbase = ((lane >> 4) & 3) * 8;
    const int arow = r0 + wv * 16 + (lane & 15);
    const float* xrow = x + (size_t)arow * CIN;

    // x tile -> fp16 registers (read once for all 3 projections)
    f16x8 a[8];
    #pragma unroll
    for (int kk = 0; kk < 8; ++kk) {
        const float4* xp = (const float4*)(xrow + kk * 32 + kbase);
        float4 x0 = xp[0], x1 = xp[1];
        float xs[8] = {x0.x, x0.y, x0.z, x0.w, x1.x, x1.y, x1.z, x1.w};
        #pragma unroll
        for (int e = 0; e < 8; ++e) a[kk][e] = (_Float16)xs[e];
    }

    const int rloc = wv * 16 + ((lane >> 4) & 3) * 4;

    #pragma unroll
    for (int m = 0; m < 3; ++m) {
        const _Float16* Wm = WT + m * (CMID * CIN);
        f32x4 acc[4] = {f32x4{0,0,0,0}, f32x4{0,0,0,0}, f32x4{0,0,0,0}, f32x4{0,0,0,0}};
        #pragma unroll
        for (int kk = 0; kk < 8; ++kk) {
            #pragma unroll
            for (int nt = 0; nt < 4; ++nt) {
                f16x8 b = *(const f16x8*)&Wm[((lane & 15) + 16 * nt) * CIN + kk * 32 + kbase];
                acc[nt] = MFMA_F16(a[kk], b, acc[nt]);
            }
        }

        if (m < 2) {
            #pragma unroll
            for (int nt = 0; nt < 4; ++nt)
                #pragma unroll
                for (int r = 0; r < 4; ++r)
                    rp[m][rloc + r][(lane & 15) + 16 * nt] = (_Float16)acc[nt][r];
        } else {
            const int rrow = r0 + rloc;
            const int b = rrow >> 12;
            const int n = rrow & (NPOS - 1);
            #pragma unroll
            for (int nt = 0; nt < 4; ++nt) {
                int cv = (lane & 15) + 16 * nt;
                union { __bf16 h[4]; uint2 u; } pk;
                #pragma unroll
                for (int r = 0; r < 4; ++r) pk.h[r] = (__bf16)acc[nt][r];
                *(uint2*)(vT_ws + ((size_t)b * CMID + cv) * NPOS + n) = pk.u;
            }
        }
    }

    __syncthreads();   // repack buffers complete
    const int row = threadIdx.x >> 3, c0 = (threadIdx.x & 7) * 8;
    #pragma unroll
    for (int h = 0; h < 2; ++h) {
        uint4 vk = *(const uint4*)&rp[0][row + 32 * h][c0];
        *(uint4*)(k_ws + (size_t)(r0 + row + 32 * h) * CMID + c0) = vk;
        uint4 vq = *(const uint4*)&rp[1][row + 32 * h][c0];
        *(uint4*)(q_ws + (size_t)(r0 + row + 32 * h) * CMID + c0) = vq;
    }
}

// ---------------------------------------------------------------------------
// flash_kernel: EXACT R12 structure (proven 45.9 us). Streaming attention,
// 32x32 swapped-QK^T, in-register P, 8 waves x 32 i-rows (block=512),
// double-buffered tiles, issue-early/write-late staging, VALU den
// (den-MFMA and setprio both regressed — R13). grid (16, 8, NSPLIT).
// ---------------------------------------------------------------------------
__global__ __launch_bounds__(512, 4) void flash_kernel(
    const _Float16* __restrict__ k_ws,  // [32768][64]
    const _Float16* __restrict__ q_ws,  // [32768][64]
    const __bf16* __restrict__ vT_ws,   // [8][64][4096]
    __bf16* __restrict__ po,            // [NSPLIT][32768][64]
    float* __restrict__ pden)           // [NSPLIT][32768]
{
    const int b = blockIdx.y;
    const int i0 = blockIdx.x * 256;
    const int sblk = blockIdx.z;
    const int jbase = sblk * (NPOS / NSPLIT);
    const int lane = threadIdx.x & 63;
    const int wv = threadIdx.x >> 6;    // 0..7
    const int l31 = lane & 31;
    const int g = lane >> 5;

    __shared__ _Float16 qt[2][64][72];
    __shared__ __bf16 vt[2][64][72];

    // wave's 32 k-rows as B-fragments
    f16x8 kf[4];
    {
        const _Float16* kp =
            k_ws + ((size_t)(b * NPOS + i0 + wv * 32 + l31)) * CMID + g * 8;
        #pragma unroll
        for (int c = 0; c < 4; ++c) kf[c] = *(const f16x8*)(kp + c * 16);
    }

    f32x16 o0 = {0,0,0,0,0,0,0,0,0,0,0,0,0,0,0,0};
    f32x16 o1 = {0,0,0,0,0,0,0,0,0,0,0,0,0,0,0,0};
    float den = 0.f;

    // staging map: 512 threads x 16B = one 64x64 fp16/bf16 tile
    const int r = threadIdx.x >> 3, c0 = (threadIdx.x & 7) * 8;
    uint4 nq, nv;

    // prologue: tile 0
    {
        nq = *(const uint4*)(q_ws + ((size_t)(b * NPOS + jbase + r)) * CMID + c0);
        nv = *(const uint4*)(vT_ws + ((size_t)b * CMID + r) * NPOS + jbase + c0);
        *(uint4*)&qt[0][r][c0] = nq;
        *(uint4*)&vt[0][r][c0] = nv;
    }
    __syncthreads();

    const int NT = (NPOS / NSPLIT) / 64;  // 16
    for (int t = 0; t < NT; ++t) {
        const int cur = t & 1;
        if (t + 1 < NT) {   // issue next-tile loads early
            int j1 = jbase + (t + 1) * 64;
            nq = *(const uint4*)(q_ws + ((size_t)(b * NPOS + j1 + r)) * CMID + c0);
            nv = *(const uint4*)(vT_ws + ((size_t)b * CMID + r) * NPOS + j1 + c0);
        }

        #pragma unroll
        for (int jj = 0; jj < 2; ++jj) {
            f16x8 aq[4];
            #pragma unroll
            for (int c = 0; c < 4; ++c)
                aq[c] = *(const f16x8*)&qt[cur][jj * 32 + l31][c * 16 + g * 8];
            bf16_8 bv00 = *(const bf16_8*)&vt[cur][l31][jj * 32 + g * 8];
            bf16_8 bv01 = *(const bf16_8*)&vt[cur][l31][jj * 32 + 16 + g * 8];
            bf16_8 bv10 = *(const bf16_8*)&vt[cur][32 + l31][jj * 32 + g * 8];
            bf16_8 bv11 = *(const bf16_8*)&vt[cur][32 + l31][jj * 32 + 16 + g * 8];

            f32x16 s = {0,0,0,0,0,0,0,0,0,0,0,0,0,0,0,0};
            s = MFMA32_F16(aq[0], kf[0], s);
            s = MFMA32_F16(aq[1], kf[1], s);
            s = MFMA32_F16(aq[2], kf[2], s);
            s = MFMA32_F16(aq[3], kf[3], s);

            unsigned pk[8];
            #pragma unroll
            for (int m = 0; m < 8; ++m) {
                float p0 = fexp2(s[2 * m]);
                float p1 = fexp2(s[2 * m + 1]);
                den += p0 + p1;
                union { __bf16 h[2]; unsigned u; } w;
                w.h[0] = (__bf16)p0; w.h[1] = (__bf16)p1;
                pk[m] = w.u;
            }
            swaplane32(pk[0], pk[2]); swaplane32(pk[1], pk[3]);
            swaplane32(pk[4], pk[6]); swaplane32(pk[5], pk[7]);
            union { unsigned u[4]; bf16_8 v; } pa0, pa1;
            pa0.u[0] = pk[0]; pa0.u[1] = pk[1]; pa0.u[2] = pk[2]; pa0.u[3] = pk[3];
            pa1.u[0] = pk[4]; pa1.u[1] = pk[5]; pa1.u[2] = pk[6]; pa1.u[3] = pk[7];

            o0 = MFMA32_BF(pa0.v, bv00, o0);
            o0 = MFMA32_BF(pa1.v, bv01, o0);
            o1 = MFMA32_BF(pa0.v, bv10, o1);
            o1 = MFMA32_BF(pa1.v, bv11, o1);
        }

        if (t + 1 < NT) {   // write-late into the other buffer
            const int nb = cur ^ 1;
            *(uint4*)&qt[nb][r][c0] = nq;
            *(uint4*)&vt[nb][r][c0] = nv;
        }
        __syncthreads();
    }

    den += __shfl_xor(den, 32);

    const size_t rowb = (size_t)b * NPOS + i0 + wv * 32;
    if (lane < 32)
        pden[(size_t)sblk * NROWS + rowb + lane] = den;

    #pragma unroll
    for (int reg = 0; reg < 16; ++reg) {
        int il = (reg & 3) + 8 * (reg >> 2) + 4 * g;
        size_t base = ((size_t)sblk * NROWS + rowb + il) * CMID + l31;
        po[base]      = (__bf16)o0[reg];
        po[base + 32] = (__bf16)o1[reg];
    }
}

// ---------------------------------------------------------------------------
// out_kernel: combine j-split partials (normalize, bf16, uint2-vectorized)
// + MFMA attn @ Wo + fused BatchNorm + LDS repack for coalesced float4
// stores. grid 2048, block 256.
// ---------------------------------------------------------------------------
__global__ __launch_bounds__(256) void out_kernel(
    const __bf16* __restrict__ po,      // [NSPLIT][32768][64]
    const float* __restrict__ pden,     // [NSPLIT][32768]
    const float* __restrict__ Wo,       // [64][256]
    const float* __restrict__ gamma, const float* __restrict__ beta,
    const float* __restrict__ mmean, const float* __restrict__ mvar,
    float* __restrict__ out)            // [32768][256]
{
    const int r0 = blockIdx.x * 16;
    const int t = threadIdx.x;
    const int lane = t & 63;
    const int wv = t >> 6;
    const int n0 = wv * 64;

    __shared__ __bf16 at[16][72];
    __shared__ float dinv[16];
    __shared__ float ot[16][260];       // output repack, pad 260 (bank-safe)

    bf16_8 wb[4][2];
    #pragma unroll
    for (int nt = 0; nt < 4; ++nt) {
        int col = n0 + nt * 16 + (lane & 15);
        #pragma unroll
        for (int ch = 0; ch < 2; ++ch)
            #pragma unroll
            for (int e = 0; e < 8; ++e)
                wb[nt][ch][e] = (__bf16)Wo[(ch * 32 + (lane >> 4) * 8 + e) * OC + col];
    }

    if (t < 16) {
        float d = 0.f;
        #pragma unroll
        for (int s = 0; s < NSPLIT; ++s) d += pden[(size_t)s * NROWS + r0 + t];
        dinv[t] = 1.0f / d;
    }
    __syncthreads();

    {   // vectorized combine: one uint2 (4 bf16) per thread, 256 quads total
        int rr = t >> 4, c4 = (t & 15) * 4;
        float s0 = 0.f, s1 = 0.f, s2 = 0.f, s3 = 0.f;
        #pragma unroll
        for (int s = 0; s < NSPLIT; ++s) {
            union { uint2 u; __bf16 h[4]; } q;
            q.u = *(const uint2*)&po[((size_t)s * NROWS + r0 + rr) * CMID + c4];
            s0 += (float)q.h[0]; s1 += (float)q.h[1];
            s2 += (float)q.h[2]; s3 += (float)q.h[3];
        }
        float di = dinv[rr];
        union { __bf16 h[4]; uint2 u; } o;
        o.h[0] = (__bf16)(s0 * di); o.h[1] = (__bf16)(s1 * di);
        o.h[2] = (__bf16)(s2 * di); o.h[3] = (__bf16)(s3 * di);
        *(uint2*)&at[rr][c4] = o.u;
    }
    __syncthreads();

    bf16_8 a0 = *(const bf16_8*)&at[lane & 15][(lane >> 4) * 8];
    bf16_8 a1 = *(const bf16_8*)&at[lane & 15][32 + (lane >> 4) * 8];

    #pragma unroll
    for (int nt = 0; nt < 4; ++nt) {
        int col = n0 + nt * 16 + (lane & 15);
        f32x4 acc = {0.f, 0.f, 0.f, 0.f};
        acc = MFMA_BF(a0, wb[nt][0], acc);
        acc = MFMA_BF(a1, wb[nt][1], acc);
        float sc = gamma[col] * rsqrtf(mvar[col] + 1e-3f);
        float sh = beta[col] - mmean[col] * sc;
        int rl = (lane >> 4) * 4;
        #pragma unroll
        for (int rr = 0; rr < 4; ++rr)
            ot[rl + rr][col] = acc[rr] * sc + sh;
    }
    __syncthreads();

    // coalesced store: 4 passes x (4 rows x 64 lanes x float4)
    {
        const int sr = t >> 6;          // 0..3 row group
        const int sc4 = (t & 63) * 4;   // dword col
        #pragma unroll
        for (int p = 0; p < 4; ++p) {
            int row = p * 4 + sr;
            float4 v = *(const float4*)&ot[row][sc4];
            *(float4*)&out[(size_t)(r0 + row) * OC + sc4] = v;
        }
    }
}

// ---------------------------------------------------------------------------
extern "C" void kernel_launch(void* const* d_in, const int* in_sizes, int n_in,
                              void* d_out, int out_size, void* d_ws, size_t ws_size,
                              hipStream_t stream) {
    const float* x     = (const float*)d_in[0];
    const float* Wk    = (const float*)d_in[1];
    const float* Wq    = (const float*)d_in[2];
    const float* Wv    = (const float*)d_in[3];
    const float* Wo    = (const float*)d_in[4];
    const float* gamma = (const float*)d_in[5];
    const float* beta  = (const float*)d_in[6];
    const float* mmean = (const float*)d_in[7];
    const float* mvar  = (const float*)d_in[8];
    float* out = (float*)d_out;

    // k/q/vT live in d_out (32 MiB): dead before out_kernel writes out.
    char* ob = (char*)d_out;
    const size_t MB4 = (size_t)NROWS * CMID * 2;   // 4 MiB
    _Float16* k_ws = (_Float16*)ob;                // 4 MiB
    _Float16* q_ws = (_Float16*)(ob + MB4);        // 4 MiB
    __bf16*   vT   = (__bf16*)(ob + 2 * MB4);      // 4 MiB

    // d_ws: po (16 MiB) + pden (512 KiB) + WT (96 KiB). ws >= 24 MiB (R2).
    __bf16*    po   = (__bf16*)d_ws;
    float*     pden = (float*)((char*)d_ws + (size_t)NSPLIT * MB4);
    _Float16*  WT   = (_Float16*)((char*)d_ws + (size_t)NSPLIT * MB4 + (size_t)NSPLIT * NROWS * 4);

    wprep_kernel<<<48, 256, 0, stream>>>(Wk, Wq, Wv, WT);
    proj_kernel<<<512, 256, 0, stream>>>(x, WT, k_ws, q_ws, vT);
    flash_kernel<<<dim3(16, 8, NSPLIT), 512, 0, stream>>>(k_ws, q_ws, vT, po, pden);
    out_kernel<<<2048, 256, 0, stream>>>(po, pden, Wo, gamma, beta, mmean, mvar, out);
}

// Round 15
// 85.173 us; speedup vs baseline: 1.1683x; 1.1683x over previous
//
#include <hip/hip_runtime.h>
#include <hip/hip_bf16.h>

typedef __bf16 bf16_8 __attribute__((ext_vector_type(8)));
typedef _Float16 f16x8 __attribute__((ext_vector_type(8)));
typedef float f32x4 __attribute__((ext_vector_type(4)));
typedef float f32x16 __attribute__((ext_vector_type(16)));

#define MFMA_BF(A, B, C)    __builtin_amdgcn_mfma_f32_16x16x32_bf16(A, B, C, 0, 0, 0)
#define MFMA_F16(A, B, C)   __builtin_amdgcn_mfma_f32_16x16x32_f16(A, B, C, 0, 0, 0)
#define MFMA32_F16(A, B, C) __builtin_amdgcn_mfma_f32_32x32x16_f16(A, B, C, 0, 0, 0)
#define MFMA32_BF(A, B, C)  __builtin_amdgcn_mfma_f32_32x32x16_bf16(A, B, C, 0, 0, 0)

#define BATCH 8
#define NPOS 4096            // 64*64 spatial
#define CIN 256
#define CMID 64
#define OC 256
#define NROWS (BATCH * NPOS) // 32768
#define NSPLIT 4             // j-split (nsplit=8 regressed: reg cap is 16 waves/CU)
#define LOG2E 1.44269504088896f

// lane i <-> lane i+32 register swap (hi half of a <-> lo half of b)
__device__ inline void swaplane32(unsigned& a, unsigned& b) {
    asm volatile("v_permlane32_swap_b32 %0, %1" : "+v"(a), "+v"(b));
}

// single-instruction 2^x. R11 LESSON: bare inline-asm v_exp_f32 is WRONG —
// trans-op forwarding hazard invisible to the compiler. Builtin is safe.
#if __has_builtin(__builtin_amdgcn_exp2f)
__device__ inline float fexp2(float x) { return __builtin_amdgcn_exp2f(x); }
#else
__device__ inline float fexp2(float x) {
    float r;
    asm("v_exp_f32 %0, %1\n\ts_nop 1" : "=v"(r) : "v"(x));  // nop INSIDE blob
    return r;
}
#endif

// ---------------------------------------------------------------------------
// proj_kernel (R12-proven): one of {k,q,v} = x @ W, all-fp16 inputs.
// Wk pre-scaled by log2e so flash uses exp2 directly. grid (512, 3),
// block 256, ONE barrier phase. R14 LESSON: W-fragments straight from
// global (scattered 512B-stride 16B loads) regressed — keep LDS staging.
// ---------------------------------------------------------------------------
__global__ __launch_bounds__(256) void proj_kernel(
    const float* __restrict__ x,
    const float* __restrict__ Wk, const float* __restrict__ Wq,
    const float* __restrict__ Wv,
    _Float16* __restrict__ k_ws, _Float16* __restrict__ q_ws,
    __bf16* __restrict__ vT_ws)
{
    const int m = blockIdx.y;
    const int r0 = blockIdx.x * 64;
    const float* W = (m == 0) ? Wk : (m == 1) ? Wq : Wv;
    const float wscale = (m == 0) ? LOG2E : 1.0f;

    __shared__ _Float16 wt[64][266];   // W^T [col][k]

    for (int idx = threadIdx.x; idx < 64 * 256; idx += 256) {
        int col = idx & 63, k = idx >> 6;
        wt[col][k] = (_Float16)(W[k * 64 + col] * wscale);
    }

    const int lane = threadIdx.x & 63;
    const int wv = threadIdx.x >> 6;
    const int kbase = ((lane >> 4) & 3) * 8;
    const int arow = r0 + wv * 16 + (lane & 15);
    const float* xrow = x + (size_t)arow * CIN;

    f16x8 a[8];
    #pragma unroll
    for (int kk = 0; kk < 8; ++kk) {
        const float4* xp = (const float4*)(xrow + kk * 32 + kbase);
        float4 x0 = xp[0], x1 = xp[1];
        float xs[8] = {x0.x, x0.y, x0.z, x0.w, x1.x, x1.y, x1.z, x1.w};
        #pragma unroll
        for (int e = 0; e < 8; ++e) a[kk][e] = (_Float16)xs[e];
    }
    __syncthreads();

    f32x4 acc[4] = {f32x4{0,0,0,0}, f32x4{0,0,0,0}, f32x4{0,0,0,0}, f32x4{0,0,0,0}};
    #pragma unroll
    for (int kk = 0; kk < 8; ++kk) {
        #pragma unroll
        for (int nt = 0; nt < 4; ++nt) {
            f16x8 b = *(const f16x8*)&wt[(lane & 15) + 16 * nt][kk * 32 + kbase];
            acc[nt] = MFMA_F16(a[kk], b, acc[nt]);
        }
    }

    const int rloc = wv * 16 + ((lane >> 4) & 3) * 4;
    if (m < 2) {
        __syncthreads();
        _Float16* rp = &wt[0][0];          // viewed as [64][72]
        #pragma unroll
        for (int nt = 0; nt < 4; ++nt)
            #pragma unroll
            for (int r = 0; r < 4; ++r)
                rp[(rloc + r) * 72 + (lane & 15) + 16 * nt] = (_Float16)acc[nt][r];
        __syncthreads();
        _Float16* dst = (m == 0) ? k_ws : q_ws;
        const int row = threadIdx.x >> 3, c0 = (threadIdx.x & 7) * 8;
        #pragma unroll
        for (int h = 0; h < 2; ++h) {
            uint4 v = *(const uint4*)&rp[(row + 32 * h) * 72 + c0];
            *(uint4*)(dst + (size_t)(r0 + row + 32 * h) * CMID + c0) = v;
        }
    } else {
        const int rrow = r0 + rloc;
        const int b = rrow >> 12;
        const int n = rrow & (NPOS - 1);
        #pragma unroll
        for (int nt = 0; nt < 4; ++nt) {
            int cv = (lane & 15) + 16 * nt;
            union { __bf16 h[4]; uint2 u; } pk;
            #pragma unroll
            for (int r = 0; r < 4; ++r) pk.h[r] = (__bf16)acc[nt][r];
            *(uint2*)(vT_ws + ((size_t)b * CMID + cv) * NPOS + n) = pk.u;
        }
    }
}

// ---------------------------------------------------------------------------
// flash_kernel: EXACT R12 structure (proven 45.9 us). Streaming attention,
// 32x32 swapped-QK^T, in-register P, 8 waves x 32 i-rows (block=512),
// double-buffered tiles, issue-early/write-late staging, VALU den
// (den-MFMA and setprio both regressed — R13). grid (16, 8, NSPLIT).
// ---------------------------------------------------------------------------
__global__ __launch_bounds__(512, 4) void flash_kernel(
    const _Float16* __restrict__ k_ws,  // [32768][64]
    const _Float16* __restrict__ q_ws,  // [32768][64]
    const __bf16* __restrict__ vT_ws,   // [8][64][4096]
    __bf16* __restrict__ po,            // [NSPLIT][32768][64]
    float* __restrict__ pden)           // [NSPLIT][32768]
{
    const int b = blockIdx.y;
    const int i0 = blockIdx.x * 256;
    const int sblk = blockIdx.z;
    const int jbase = sblk * (NPOS / NSPLIT);
    const int lane = threadIdx.x & 63;
    const int wv = threadIdx.x >> 6;    // 0..7
    const int l31 = lane & 31;
    const int g = lane >> 5;

    __shared__ _Float16 qt[2][64][72];
    __shared__ __bf16 vt[2][64][72];

    // wave's 32 k-rows as B-fragments
    f16x8 kf[4];
    {
        const _Float16* kp =
            k_ws + ((size_t)(b * NPOS + i0 + wv * 32 + l31)) * CMID + g * 8;
        #pragma unroll
        for (int c = 0; c < 4; ++c) kf[c] = *(const f16x8*)(kp + c * 16);
    }

    f32x16 o0 = {0,0,0,0,0,0,0,0,0,0,0,0,0,0,0,0};
    f32x16 o1 = {0,0,0,0,0,0,0,0,0,0,0,0,0,0,0,0};
    float den = 0.f;

    // staging map: 512 threads x 16B = one 64x64 fp16/bf16 tile
    const int r = threadIdx.x >> 3, c0 = (threadIdx.x & 7) * 8;
    uint4 nq, nv;

    // prologue: tile 0
    {
        nq = *(const uint4*)(q_ws + ((size_t)(b * NPOS + jbase + r)) * CMID + c0);
        nv = *(const uint4*)(vT_ws + ((size_t)b * CMID + r) * NPOS + jbase + c0);
        *(uint4*)&qt[0][r][c0] = nq;
        *(uint4*)&vt[0][r][c0] = nv;
    }
    __syncthreads();

    const int NT = (NPOS / NSPLIT) / 64;  // 16
    for (int t = 0; t < NT; ++t) {
        const int cur = t & 1;
        if (t + 1 < NT) {   // issue next-tile loads early
            int j1 = jbase + (t + 1) * 64;
            nq = *(const uint4*)(q_ws + ((size_t)(b * NPOS + j1 + r)) * CMID + c0);
            nv = *(const uint4*)(vT_ws + ((size_t)b * CMID + r) * NPOS + j1 + c0);
        }

        #pragma unroll
        for (int jj = 0; jj < 2; ++jj) {
            f16x8 aq[4];
            #pragma unroll
            for (int c = 0; c < 4; ++c)
                aq[c] = *(const f16x8*)&qt[cur][jj * 32 + l31][c * 16 + g * 8];
            bf16_8 bv00 = *(const bf16_8*)&vt[cur][l31][jj * 32 + g * 8];
            bf16_8 bv01 = *(const bf16_8*)&vt[cur][l31][jj * 32 + 16 + g * 8];
            bf16_8 bv10 = *(const bf16_8*)&vt[cur][32 + l31][jj * 32 + g * 8];
            bf16_8 bv11 = *(const bf16_8*)&vt[cur][32 + l31][jj * 32 + 16 + g * 8];

            f32x16 s = {0,0,0,0,0,0,0,0,0,0,0,0,0,0,0,0};
            s = MFMA32_F16(aq[0], kf[0], s);
            s = MFMA32_F16(aq[1], kf[1], s);
            s = MFMA32_F16(aq[2], kf[2], s);
            s = MFMA32_F16(aq[3], kf[3], s);

            unsigned pk[8];
            #pragma unroll
            for (int m = 0; m < 8; ++m) {
                float p0 = fexp2(s[2 * m]);
                float p1 = fexp2(s[2 * m + 1]);
                den += p0 + p1;
                union { __bf16 h[2]; unsigned u; } w;
                w.h[0] = (__bf16)p0; w.h[1] = (__bf16)p1;
                pk[m] = w.u;
            }
            swaplane32(pk[0], pk[2]); swaplane32(pk[1], pk[3]);
            swaplane32(pk[4], pk[6]); swaplane32(pk[5], pk[7]);
            union { unsigned u[4]; bf16_8 v; } pa0, pa1;
            pa0.u[0] = pk[0]; pa0.u[1] = pk[1]; pa0.u[2] = pk[2]; pa0.u[3] = pk[3];
            pa1.u[0] = pk[4]; pa1.u[1] = pk[5]; pa1.u[2] = pk[6]; pa1.u[3] = pk[7];

            o0 = MFMA32_BF(pa0.v, bv00, o0);
            o0 = MFMA32_BF(pa1.v, bv01, o0);
            o1 = MFMA32_BF(pa0.v, bv10, o1);
            o1 = MFMA32_BF(pa1.v, bv11, o1);
        }

        if (t + 1 < NT) {   // write-late into the other buffer
            const int nb = cur ^ 1;
            *(uint4*)&qt[nb][r][c0] = nq;
            *(uint4*)&vt[nb][r][c0] = nv;
        }
        __syncthreads();
    }

    den += __shfl_xor(den, 32);

    const size_t rowb = (size_t)b * NPOS + i0 + wv * 32;
    if (lane < 32)
        pden[(size_t)sblk * NROWS + rowb + lane] = den;

    #pragma unroll
    for (int reg = 0; reg < 16; ++reg) {
        int il = (reg & 3) + 8 * (reg >> 2) + 4 * g;
        size_t base = ((size_t)sblk * NROWS + rowb + il) * CMID + l31;
        po[base]      = (__bf16)o0[reg];
        po[base + 32] = (__bf16)o1[reg];
    }
}

// ---------------------------------------------------------------------------
// out_kernel v2: 64 rows per block (grid 512) — Wo register-preload
// amortized 4x vs the 2048-block version (cuts ~100 MB of scattered L2
// traffic). Combine j-split partials (uint2-vectorized) -> at bf16 ->
// rowgroup-looped MFMA attn @ Wo -> fused BatchNorm -> direct stores
// (64B row segments). block 256 (4 waves, wave wv owns cols wv*64..+63).
// ---------------------------------------------------------------------------
__global__ __launch_bounds__(256) void out_kernel(
    const __bf16* __restrict__ po,      // [NSPLIT][32768][64]
    const float* __restrict__ pden,     // [NSPLIT][32768]
    const float* __restrict__ Wo,       // [64][256]
    const float* __restrict__ gamma, const float* __restrict__ beta,
    const float* __restrict__ mmean, const float* __restrict__ mvar,
    float* __restrict__ out)            // [32768][256]
{
    const int r0 = blockIdx.x * 64;
    const int t = threadIdx.x;
    const int lane = t & 63;
    const int wv = t >> 6;
    const int n0 = wv * 64;

    __shared__ __bf16 at[64][72];
    __shared__ float dinv[64];

    // Wo B-fragments from global (L2-hot), bf16 cast — issued early
    bf16_8 wb[4][2];
    #pragma unroll
    for (int nt = 0; nt < 4; ++nt) {
        int col = n0 + nt * 16 + (lane & 15);
        #pragma unroll
        for (int ch = 0; ch < 2; ++ch)
            #pragma unroll
            for (int e = 0; e < 8; ++e)
                wb[nt][ch][e] = (__bf16)Wo[(ch * 32 + (lane >> 4) * 8 + e) * OC + col];
    }

    // BN constants per owned column (4 cols/thread)
    float scs[4], shs[4];
    #pragma unroll
    for (int nt = 0; nt < 4; ++nt) {
        int col = n0 + nt * 16 + (lane & 15);
        scs[nt] = gamma[col] * rsqrtf(mvar[col] + 1e-3f);
        shs[nt] = beta[col] - mmean[col] * scs[nt];
    }

    if (t < 64) {
        float d = 0.f;
        #pragma unroll
        for (int s = 0; s < NSPLIT; ++s) d += pden[(size_t)s * NROWS + r0 + t];
        dinv[t] = 1.0f / d;
    }
    __syncthreads();

    // vectorized combine: 64x64 = 1024 quads, 4 per thread
    #pragma unroll
    for (int q = 0; q < 4; ++q) {
        int quad = t + q * 256;
        int rr = quad >> 4, c4 = (quad & 15) * 4;
        float s0 = 0.f, s1 = 0.f, s2 = 0.f, s3 = 0.f;
        #pragma unroll
        for (int s = 0; s < NSPLIT; ++s) {
            union { uint2 u; __bf16 h[4]; } qq;
            qq.u = *(const uint2*)&po[((size_t)s * NROWS + r0 + rr) * CMID + c4];
            s0 += (float)qq.h[0]; s1 += (float)qq.h[1];
            s2 += (float)qq.h[2]; s3 += (float)qq.h[3];
        }
        float di = dinv[rr];
        union { __bf16 h[4]; uint2 u; } o;
        o.h[0] = (__bf16)(s0 * di); o.h[1] = (__bf16)(s1 * di);
        o.h[2] = (__bf16)(s2 * di); o.h[3] = (__bf16)(s3 * di);
        *(uint2*)&at[rr][c4] = o.u;
    }
    __syncthreads();

    // rowgroup-looped MFMA: 4 groups of 16 rows; acc live range = 16 f32
    #pragma unroll
    for (int rg = 0; rg < 4; ++rg) {
        bf16_8 a0 = *(const bf16_8*)&at[rg * 16 + (lane & 15)][(lane >> 4) * 8];
        bf16_8 a1 = *(const bf16_8*)&at[rg * 16 + (lane & 15)][32 + (lane >> 4) * 8];
        #pragma unroll
        for (int nt = 0; nt < 4; ++nt) {
            int col = n0 + nt * 16 + (lane & 15);
            f32x4 acc = {0.f, 0.f, 0.f, 0.f};
            acc = MFMA_BF(a0, wb[nt][0], acc);
            acc = MFMA_BF(a1, wb[nt][1], acc);
            int rl = rg * 16 + (lane >> 4) * 4;
            #pragma unroll
            for (int rr = 0; rr < 4; ++rr)
                out[(size_t)(r0 + rl + rr) * OC + col] = acc[rr] * scs[nt] + shs[nt];
        }
    }
}

// ---------------------------------------------------------------------------
extern "C" void kernel_launch(void* const* d_in, const int* in_sizes, int n_in,
                              void* d_out, int out_size, void* d_ws, size_t ws_size,
                              hipStream_t stream) {
    const float* x     = (const float*)d_in[0];
    const float* Wk    = (const float*)d_in[1];
    const float* Wq    = (const float*)d_in[2];
    const float* Wv    = (const float*)d_in[3];
    const float* Wo    = (const float*)d_in[4];
    const float* gamma = (const float*)d_in[5];
    const float* beta  = (const float*)d_in[6];
    const float* mmean = (const float*)d_in[7];
    const float* mvar  = (const float*)d_in[8];
    float* out = (float*)d_out;

    // k/q/vT live in d_out (32 MiB): dead before out_kernel writes out.
    char* ob = (char*)d_out;
    const size_t MB4 = (size_t)NROWS * CMID * 2;   // 4 MiB
    _Float16* k_ws = (_Float16*)ob;                // 4 MiB
    _Float16* q_ws = (_Float16*)(ob + MB4);        // 4 MiB
    __bf16*   vT   = (__bf16*)(ob + 2 * MB4);      // 4 MiB

    __bf16* po   = (__bf16*)d_ws;                                 // 16 MiB
    float*  pden = (float*)((char*)d_ws + (size_t)NSPLIT * MB4);  // 512 KiB

    proj_kernel<<<dim3(512, 3), 256, 0, stream>>>(x, Wk, Wq, Wv, k_ws, q_ws, vT);
    flash_kernel<<<dim3(16, 8, NSPLIT), 512, 0, stream>>>(k_ws, q_ws, vT, po, pden);
    out_kernel<<<512, 256, 0, stream>>>(po, pden, Wo, gamma, beta, mmean, mvar, out);
}